// Round 4
// baseline (150.401 us; speedup 1.0000x reference)
//
#include <hip/hip_runtime.h>
#include <math.h>

// IMPACT modality argmin — lane-per-(query,modality) layout.
//
// Pipeline (all on `stream`):
//   1. memsetAsync hist=0
//   2. impact_hist:    hist[item] += 1 over all queries
//   3. impact_scan:    cursor = exclusive prefix sum of hist (1 block)
//   4. impact_scatter: perm[atomicAdd(cursor[item])] = query (groups by item)
//   5. impact_main:    16 lanes per query, lane l owns modality m=l+1
//                      (clamped to nb -> no extra cache lines). Each lane
//                      serially accumulates the full 128-dim distance in 4
//                      independent f64 chains; ONE 4-round argmin butterfly
//                      per query at the end (vs 8 shuffles per row before).
//                      Sorted order -> item rows served from L1/L2.
//
// Distances: f32 subtract (bit-identical to the f32 reference diff), then
// exact f64 square+accumulate -> our p is the TRUE value of the reference's
// f32-diff sum; proven absmax 0.0 in rounds 1-3.

#define M_TOT 14
#define CDIM 128

__global__ void impact_hist(const int* __restrict__ item_ids,
                            int* __restrict__ hist, int B) {
    int i = blockIdx.x * blockDim.x + threadIdx.x;
    if (i < B) atomicAdd(&hist[item_ids[i]], 1);
}

__global__ __launch_bounds__(1024) void impact_scan(const int* __restrict__ hist,
                                                    int* __restrict__ cursor, int n) {
    __shared__ int partial[1024];
    int tid = threadIdx.x;
    int ch = (n + 1023) >> 10;
    int base = tid * ch;
    int s = 0;
    for (int j = 0; j < ch; ++j) {
        int k = base + j;
        if (k < n) s += hist[k];
    }
    partial[tid] = s;
    __syncthreads();
    for (int off = 1; off < 1024; off <<= 1) {
        int v = (tid >= off) ? partial[tid - off] : 0;
        __syncthreads();
        partial[tid] += v;
        __syncthreads();
    }
    int run = (tid > 0) ? partial[tid - 1] : 0;
    for (int j = 0; j < ch; ++j) {
        int k = base + j;
        if (k < n) { cursor[k] = run; run += hist[k]; }
    }
}

__global__ void impact_scatter(const int* __restrict__ item_ids,
                               int* __restrict__ cursor,
                               int* __restrict__ perm, int B) {
    int i = blockIdx.x * blockDim.x + threadIdx.x;
    if (i < B) {
        int pos = atomicAdd(&cursor[item_ids[i]], 1);
        perm[pos] = i;
    }
}

__global__ __launch_bounds__(256) void impact_main(
    const int* __restrict__ user_ids,
    const int* __restrict__ item_ids,
    const float* __restrict__ users_emb,   // [USER_N, 128]
    const float* __restrict__ item_emb,    // [ITEM_N*14, 128]
    const int* __restrict__ nb_mod,        // [ITEM_N]
    const int* __restrict__ perm,          // may be null (unsorted fallback)
    float* __restrict__ out,
    int B)
{
    // chunked XCD mapping: consecutive sorted blocks -> same XCD L2
    int p = blockIdx.x;
    int lb = p;
    if ((gridDim.x & 7) == 0) {
        int cpx = gridDim.x >> 3;
        lb = (p & 7) * cpx + (p >> 3);
    }

    int g = threadIdx.x >> 4;          // query slot within block (0..15)
    int l = threadIdx.x & 15;          // modality lane
    int qi = lb * 16 + g;
    if (qi >= B) return;
    int q = perm ? perm[qi] : qi;

    int uid = user_ids[q];
    int iid = item_ids[q];
    int nb  = nb_mod[iid];             // [2,12]; valid modality cols 1..nb

    int m = l + 1;                     // this lane's modality
    bool valid = (m <= nb);
    int mld = valid ? m : nb;          // clamp -> only rows 1..nb touched

    const float4* urow = (const float4*)(users_emb + (size_t)uid * CDIM);
    const float4* vrow = (const float4*)(item_emb + ((size_t)iid * M_TOT + mld) * CDIM);

    double a0 = 0.0, a1 = 0.0, a2 = 0.0, a3 = 0.0;
#pragma unroll 4
    for (int c = 0; c < CDIM / 4; ++c) {
        float4 u = urow[c];            // lane-uniform -> broadcast line
        float4 v = vrow[c];
        float d0 = u.x - v.x;
        float d1 = u.y - v.y;
        float d2 = u.z - v.z;
        float d3 = u.w - v.w;
        a0 += (double)d0 * d0;
        a1 += (double)d1 * d1;
        a2 += (double)d2 * d2;
        a3 += (double)d3 * d3;
    }
    double s = (a0 + a1) + (a2 + a3);
    if (!valid) s = INFINITY;
    int idx = m;

    // 16-lane argmin butterfly; tie -> smaller modality (first occurrence)
#pragma unroll
    for (int off = 1; off < 16; off <<= 1) {
        double so = __shfl_xor(s, off);
        int    io = __shfl_xor(idx, off);
        if (so < s || (so == s && io < idx)) { s = so; idx = io; }
    }

    if (l == 0)
        out[q] = (float)(idx - 1) / (float)(nb - 1) + 1.0f;
}

extern "C" void kernel_launch(void* const* d_in, const int* in_sizes, int n_in,
                              void* d_out, int out_size, void* d_ws, size_t ws_size,
                              hipStream_t stream) {
    // inputs: 0 user_ids, 1 item_ids, 2 concept_ids (unused),
    //         3 users_emb_weight, 4 item_resp_emb_weight,
    //         5 mask (unused; nb_modalities carries the same info), 6 nb_modalities
    const int*   user_ids  = (const int*)d_in[0];
    const int*   item_ids  = (const int*)d_in[1];
    const float* users_emb = (const float*)d_in[3];
    const float* item_emb  = (const float*)d_in[4];
    const int*   nb_mod    = (const int*)d_in[6];
    float* out = (float*)d_out;

    int B = in_sizes[0];
    int n_items = in_sizes[6];

    // ws layout: hist[n_items] | cursor[n_items] | perm[B]
    size_t need = ((size_t)n_items * 2 + (size_t)B) * sizeof(int);
    int* perm = nullptr;

    if (ws_size >= need) {
        int* hist   = (int*)d_ws;
        int* cursor = hist + n_items;
        perm        = cursor + n_items;

        hipMemsetAsync(hist, 0, (size_t)n_items * sizeof(int), stream);
        impact_hist<<<(B + 255) / 256, 256, 0, stream>>>(item_ids, hist, B);
        impact_scan<<<1, 1024, 0, stream>>>(hist, cursor, n_items);
        impact_scatter<<<(B + 255) / 256, 256, 0, stream>>>(item_ids, cursor, perm, B);
    }

    int grid = (B + 15) / 16;          // 16 queries per 256-thread block
    impact_main<<<grid, 256, 0, stream>>>(
        user_ids, item_ids, users_emb, item_emb, nb_mod, perm, out, B);
}

// Round 5
// 96.869 us; speedup vs baseline: 1.5526x; 1.5526x over previous
//
#include <hip/hip_runtime.h>
#include <math.h>

// IMPACT modality argmin — coalesced row loads + per-lane per-row f32
// partials + one LDS transpose per query + single argmin butterfly.
// Near-ties (f32 gap < TAU) are re-solved exactly in f64 by a tiny
// refinement kernel (R1's proven-exact semantics).
//
// Pipeline (all on `stream`):
//   1. memsetAsync: hist + flag_cnt = 0
//   2. impact_hist / impact_scan / impact_scatter: counting sort by item
//      (perm groups same-item queries -> item rows L1/L2-resident; FETCH
//      proved to drop 250->74 MB in rounds 3-4)
//   3. impact_main: 16 lanes span a row (fully coalesced float4 loads,
//      few cache lines per instr -- R4 showed divergent rows cost
//      ~1 line/cy/CU = 116 us). Lane keeps acc[m] (m<12) f32 partials over
//      its 8 dims; rows independent -> deep ILP, NO cross-lane per row.
//      Then LDS transpose (65-word row stride -> 2-way banks) gives lane m
//      row m's 16 partials; serial sum; ONE 16-lane argmin butterfly
//      tracking (best, idx, second). gap < TAU -> flag for refinement.
//   4. impact_refine: flagged queries recomputed in exact f64 (bit-path
//      identical to rounds 1-4 which scored absmax 0.0).

#define M_TOT 14
#define CDIM 128
#define TAU 0.05f

// ---------------- prep: counting sort by item ----------------
__global__ void impact_hist(const int* __restrict__ item_ids,
                            int* __restrict__ hist, int B) {
    int i = blockIdx.x * blockDim.x + threadIdx.x;
    if (i < B) atomicAdd(&hist[item_ids[i]], 1);
}

__global__ __launch_bounds__(1024) void impact_scan(const int* __restrict__ hist,
                                                    int* __restrict__ cursor, int n) {
    __shared__ int partial[1024];
    int tid = threadIdx.x;
    int ch = (n + 1023) >> 10;
    int base = tid * ch;
    int s = 0;
    for (int j = 0; j < ch; ++j) {
        int k = base + j;
        if (k < n) s += hist[k];
    }
    partial[tid] = s;
    __syncthreads();
    for (int off = 1; off < 1024; off <<= 1) {
        int v = (tid >= off) ? partial[tid - off] : 0;
        __syncthreads();
        partial[tid] += v;
        __syncthreads();
    }
    int run = (tid > 0) ? partial[tid - 1] : 0;
    for (int j = 0; j < ch; ++j) {
        int k = base + j;
        if (k < n) { cursor[k] = run; run += hist[k]; }
    }
}

__global__ void impact_scatter(const int* __restrict__ item_ids,
                               int* __restrict__ cursor,
                               int* __restrict__ perm, int B) {
    int i = blockIdx.x * blockDim.x + threadIdx.x;
    if (i < B) {
        int pos = atomicAdd(&cursor[item_ids[i]], 1);
        perm[pos] = i;
    }
}

// ---------------- main kernel ----------------
__global__ __launch_bounds__(256) void impact_main(
    const int* __restrict__ user_ids,
    const int* __restrict__ item_ids,
    const float* __restrict__ users_emb,   // [USER_N, 128]
    const float* __restrict__ item_emb,    // [ITEM_N*14, 128]
    const int* __restrict__ nb_mod,        // [ITEM_N]
    const int* __restrict__ perm,          // may be null
    float* __restrict__ out,
    int* __restrict__ flag_cnt,
    int* __restrict__ flag_list,
    int B)
{
    // per-wave transpose scratch: 12 rows x (4 groups x 16 lanes), row
    // stride 65 words -> write/read both 2-way bank aliasing (free)
    __shared__ float xpose[4 * 780];

    // chunked XCD mapping: consecutive sorted blocks -> same XCD L2
    int p = blockIdx.x;
    int lb = p;
    if ((gridDim.x & 7) == 0) {
        int cpx = gridDim.x >> 3;
        lb = (p & 7) * cpx + (p >> 3);
    }

    int w = threadIdx.x >> 6;          // wave 0..3
    int g = (threadIdx.x >> 4) & 3;    // 16-lane group in wave
    int l = threadIdx.x & 15;
    int qi = lb * 16 + w * 4 + g;      // 16 queries per block

    bool vq = qi < B;
    int q   = vq ? (perm ? perm[qi] : qi) : 0;
    int uid = vq ? user_ids[q] : 0;
    int iid = vq ? item_ids[q] : 0;
    int nb  = vq ? nb_mod[iid] : 2;    // [2,12]

    const float4* urow = (const float4*)(users_emb + (size_t)uid * CDIM);
    float4 u0 = urow[l];
    float4 u1 = urow[l + 16];

    const float4* vbase =
        (const float4*)(item_emb + ((size_t)iid * M_TOT + 1) * CDIM);

    float acc[12];
#pragma unroll
    for (int m = 0; m < 12; ++m) acc[m] = 0.0f;

    // row phase: fully unrolled (static acc indices), predicated per group;
    // wave cost = max nb over its 4 groups (sorted -> usually equal)
#pragma unroll
    for (int m = 0; m < 12; ++m) {
        if (m < nb) {
            const float4* vr = vbase + (size_t)m * (CDIM / 4);
            float4 v0 = vr[l];
            float4 v1 = vr[l + 16];
            float d0 = u0.x - v0.x, d1 = u0.y - v0.y;
            float d2 = u0.z - v0.z, d3 = u0.w - v0.w;
            float d4 = u1.x - v1.x, d5 = u1.y - v1.y;
            float d6 = u1.z - v1.z, d7 = u1.w - v1.w;
            acc[m] = ((d0 * d0 + d1 * d1) + (d2 * d2 + d3 * d3))
                   + ((d4 * d4 + d5 * d5) + (d6 * d6 + d7 * d7));
        }
    }

    // transpose: [m][group][lane], row stride 65
    float* X = xpose + w * 780;
#pragma unroll
    for (int m = 0; m < 12; ++m)
        X[m * 65 + g * 16 + l] = acc[m];

    __syncthreads();

    // lane m sums row m's 16 partials
    int lm = (l < 12) ? l : 0;
    const float* R = X + lm * 65 + g * 16;
    float t0 = 0.f, t1 = 0.f, t2 = 0.f, t3 = 0.f;
#pragma unroll
    for (int r = 0; r < 4; ++r) {
        t0 += R[r];
        t1 += R[4 + r];
        t2 += R[8 + r];
        t3 += R[12 + r];
    }
    float s = (t0 + t1) + (t2 + t3);
    if (l >= nb) s = INFINITY;         // invalid modality lanes

    // single 16-lane argmin butterfly tracking (best, idx, second-best)
    float b1 = s, b2 = INFINITY;
    int i1 = l + 1;
#pragma unroll
    for (int off = 1; off < 16; off <<= 1) {
        float ob1 = __shfl_xor(b1, off);
        float ob2 = __shfl_xor(b2, off);
        int   oi1 = __shfl_xor(i1, off);
        float lo = fminf(b1, ob1);
        float hi = fmaxf(b1, ob1);
        if (ob1 < b1 || (ob1 == b1 && oi1 < i1)) i1 = oi1;
        b1 = lo;
        b2 = fminf(fminf(b2, ob2), hi);
    }

    if (l == 0 && vq) {
        out[q] = (float)(i1 - 1) / (float)(nb - 1) + 1.0f;
        if (b2 - b1 < TAU) {           // f32 decision not provably safe
            int pos = atomicAdd(flag_cnt, 1);
            flag_list[pos] = q;
        }
    }
}

// ---------------- exact f64 refinement (rare) ----------------
__global__ __launch_bounds__(256) void impact_refine(
    const int* __restrict__ user_ids,
    const int* __restrict__ item_ids,
    const float* __restrict__ users_emb,
    const float* __restrict__ item_emb,
    const int* __restrict__ nb_mod,
    const int* __restrict__ flag_cnt,
    const int* __restrict__ flag_list,
    float* __restrict__ out)
{
    int cnt = *flag_cnt;
    int ngrp = (gridDim.x * blockDim.x) >> 4;
    int gid = (blockIdx.x * blockDim.x + threadIdx.x) >> 4;
    int l = threadIdx.x & 15;

    for (int i = gid; i < cnt; i += ngrp) {
        int q = flag_list[i];
        int uid = user_ids[q];
        int iid = item_ids[q];
        int nb  = nb_mod[iid];

        const float4* urow = (const float4*)(users_emb + (size_t)uid * CDIM);
        float4 u0 = urow[l];
        float4 u1 = urow[l + 16];

        double best = 1e300;
        int bidx = 1;
        const float4* ibase =
            (const float4*)(item_emb + ((size_t)iid * M_TOT + 1) * CDIM);

        for (int m = 1; m <= nb; ++m) {
            const float4* vr = ibase + (size_t)(m - 1) * (CDIM / 4);
            float4 v0 = vr[l];
            float4 v1 = vr[l + 16];
            float d;
            double sd = 0.0;
            d = u0.x - v0.x; sd += (double)d * d;
            d = u0.y - v0.y; sd += (double)d * d;
            d = u0.z - v0.z; sd += (double)d * d;
            d = u0.w - v0.w; sd += (double)d * d;
            d = u1.x - v1.x; sd += (double)d * d;
            d = u1.y - v1.y; sd += (double)d * d;
            d = u1.z - v1.z; sd += (double)d * d;
            d = u1.w - v1.w; sd += (double)d * d;
            sd += __shfl_xor(sd, 1);
            sd += __shfl_xor(sd, 2);
            sd += __shfl_xor(sd, 4);
            sd += __shfl_xor(sd, 8);
            if (sd < best) { best = sd; bidx = m; }
        }
        if (l == 0)
            out[q] = (float)(bidx - 1) / (float)(nb - 1) + 1.0f;
    }
}

extern "C" void kernel_launch(void* const* d_in, const int* in_sizes, int n_in,
                              void* d_out, int out_size, void* d_ws, size_t ws_size,
                              hipStream_t stream) {
    // inputs: 0 user_ids, 1 item_ids, 2 concept_ids (unused),
    //         3 users_emb_weight, 4 item_resp_emb_weight,
    //         5 mask (unused; nb_modalities carries the same info), 6 nb_modalities
    const int*   user_ids  = (const int*)d_in[0];
    const int*   item_ids  = (const int*)d_in[1];
    const float* users_emb = (const float*)d_in[3];
    const float* item_emb  = (const float*)d_in[4];
    const int*   nb_mod    = (const int*)d_in[6];
    float* out = (float*)d_out;

    int B = in_sizes[0];
    int n_items = in_sizes[6];

    // ws layout (ints): hist[n_items] | flag_cnt[1] | pad[3] | cursor[n_items]
    //                   | perm[B] | flag_list[B]
    size_t need = ((size_t)n_items * 2 + 4 + 2 * (size_t)B) * sizeof(int);
    int* hist      = (int*)d_ws;
    int* flag_cnt  = hist + n_items;
    int* cursor    = flag_cnt + 4;
    int* perm      = cursor + n_items;
    int* flag_list = perm + B;

    bool sorted = ws_size >= need;
    if (sorted) {
        // one memset covers hist + flag_cnt (+pad)
        hipMemsetAsync(hist, 0, ((size_t)n_items + 4) * sizeof(int), stream);
        impact_hist<<<(B + 255) / 256, 256, 0, stream>>>(item_ids, hist, B);
        impact_scan<<<1, 1024, 0, stream>>>(hist, cursor, n_items);
        impact_scatter<<<(B + 255) / 256, 256, 0, stream>>>(item_ids, cursor, perm, B);
    }

    int grid = (B + 15) / 16;          // 16 queries per 256-thread block
    impact_main<<<grid, 256, 0, stream>>>(
        user_ids, item_ids, users_emb, item_emb, nb_mod,
        sorted ? perm : nullptr, out,
        sorted ? flag_cnt : nullptr, sorted ? flag_list : nullptr, B);

    if (sorted)
        impact_refine<<<64, 256, 0, stream>>>(
            user_ids, item_ids, users_emb, item_emb, nb_mod,
            flag_cnt, flag_list, out);
}

// Round 6
// 76.669 us; speedup vs baseline: 1.9617x; 1.2635x over previous
//
#include <hip/hip_runtime.h>
#include <math.h>

// IMPACT modality argmin — R6: parallel 2-level scan prep + 4-row-batched
// (MLP=8) main kernel. Near-ties (f32 gap < TAU) re-solved exactly in f64.
//
// Pipeline (all on `stream`):
//   1. memsetAsync: hist + flag_cnt = 0
//   2. impact_hist (int4-vectorized) -> hist[item]
//   3. impact_scan_part: 79 blocks, per-256-chunk LDS exclusive scan -> cursor,
//      block sums -> bsum
//   4. impact_scan_top: 1 block scans bsum -> boffs (exclusive)
//   5. impact_scatter: pos = atomicAdd(cursor[item]) + boffs[item>>8];
//      perm[pos] = query  (same-item queries adjacent -> item rows L1/L2-hit;
//      FETCH proven 250->74 MB in rounds 3-5)
//   6. impact_main: 16 lanes span a row (coalesced float4); rows processed in
//      batches of 4 with ALL 8 loads issued before first use (R5's VGPR=28
//      showed the compiler serialized load->use per row, MLP~2 -> latency
//      bound). Row partial written straight to LDS (stride 65 -> 2-way banks,
//      free). One barrier, lane-m serial sum, ONE 16-lane argmin butterfly
//      tracking (best, idx, second). gap < TAU -> flag.
//   7. impact_refine: flagged queries recomputed in exact f64 (bit-path
//      identical to rounds 1-5, absmax 0.0 every round).

#define M_TOT 14
#define CDIM 128
#define TAU 0.05f

// ---------------- prep: counting sort by item ----------------
__global__ void impact_hist(const int* __restrict__ item_ids,
                            int* __restrict__ hist, int B) {
    int i = blockIdx.x * blockDim.x + threadIdx.x;
    int i4 = i * 4;
    if (i4 + 3 < B) {
        int4 v = *(const int4*)(item_ids + i4);
        atomicAdd(&hist[v.x], 1);
        atomicAdd(&hist[v.y], 1);
        atomicAdd(&hist[v.z], 1);
        atomicAdd(&hist[v.w], 1);
    } else {
        for (int k = i4; k < B; ++k) atomicAdd(&hist[k - i4 + i4 + 0], 0); // no-op guard
        for (int k = i4; k < B; ++k) atomicAdd(&hist[item_ids[k]], 1);
    }
}

__global__ __launch_bounds__(256) void impact_scan_part(
    const int* __restrict__ hist, int* __restrict__ cursor,
    int* __restrict__ bsum, int n) {
    __shared__ int sd[256];
    int t = threadIdx.x;
    int k = blockIdx.x * 256 + t;
    int v = (k < n) ? hist[k] : 0;
    sd[t] = v;
    __syncthreads();
#pragma unroll
    for (int off = 1; off < 256; off <<= 1) {
        int x = (t >= off) ? sd[t - off] : 0;
        __syncthreads();
        sd[t] += x;
        __syncthreads();
    }
    if (k < n) cursor[k] = sd[t] - v;          // exclusive within chunk
    if (t == 255) bsum[blockIdx.x] = sd[255];  // chunk total
}

__global__ __launch_bounds__(128) void impact_scan_top(
    const int* __restrict__ bsum, int* __restrict__ boffs, int nblk) {
    __shared__ int sd[128];
    int t = threadIdx.x;
    int v = (t < nblk) ? bsum[t] : 0;
    sd[t] = v;
    __syncthreads();
#pragma unroll
    for (int off = 1; off < 128; off <<= 1) {
        int x = (t >= off) ? sd[t - off] : 0;
        __syncthreads();
        sd[t] += x;
        __syncthreads();
    }
    if (t < nblk) boffs[t] = sd[t] - v;        // exclusive block offset
}

__global__ void impact_scatter(const int* __restrict__ item_ids,
                               int* __restrict__ cursor,
                               const int* __restrict__ boffs,
                               int* __restrict__ perm, int B) {
    int i = blockIdx.x * blockDim.x + threadIdx.x;
    int i4 = i * 4;
    if (i4 + 3 < B) {
        int4 v = *(const int4*)(item_ids + i4);
        int p0 = atomicAdd(&cursor[v.x], 1) + boffs[v.x >> 8];
        int p1 = atomicAdd(&cursor[v.y], 1) + boffs[v.y >> 8];
        int p2 = atomicAdd(&cursor[v.z], 1) + boffs[v.z >> 8];
        int p3 = atomicAdd(&cursor[v.w], 1) + boffs[v.w >> 8];
        perm[p0] = i4;
        perm[p1] = i4 + 1;
        perm[p2] = i4 + 2;
        perm[p3] = i4 + 3;
    } else {
        for (int k = i4; k < B; ++k) {
            int it = item_ids[k];
            int p = atomicAdd(&cursor[it], 1) + boffs[it >> 8];
            perm[p] = k;
        }
    }
}

// ---------------- main kernel ----------------
__global__ __launch_bounds__(256) void impact_main(
    const int* __restrict__ user_ids,
    const int* __restrict__ item_ids,
    const float* __restrict__ users_emb,   // [USER_N, 128]
    const float* __restrict__ item_emb,    // [ITEM_N*14, 128]
    const int* __restrict__ nb_mod,        // [ITEM_N]
    const int* __restrict__ perm,          // may be null
    float* __restrict__ out,
    int* __restrict__ flag_cnt,
    int* __restrict__ flag_list,
    int B)
{
    // per-wave transpose scratch: 12 rows x (4 groups x 16 lanes), stride 65
    __shared__ float xpose[4 * 780];

    // chunked XCD mapping: consecutive sorted blocks -> same XCD L2
    int p = blockIdx.x;
    int lb = p;
    if ((gridDim.x & 7) == 0) {
        int cpx = gridDim.x >> 3;
        lb = (p & 7) * cpx + (p >> 3);
    }

    int w = threadIdx.x >> 6;          // wave 0..3
    int g = (threadIdx.x >> 4) & 3;    // 16-lane group in wave
    int l = threadIdx.x & 15;
    int qi = lb * 16 + w * 4 + g;      // 16 queries per block

    bool vq = qi < B;
    int q   = vq ? (perm ? perm[qi] : qi) : 0;
    int uid = vq ? user_ids[q] : 0;
    int iid = vq ? item_ids[q] : 0;
    int nb  = vq ? nb_mod[iid] : 2;    // [2,12]

    const float4* urow = (const float4*)(users_emb + (size_t)uid * CDIM);
    float4 u0 = urow[l];
    float4 u1 = urow[l + 16];

    const float4* vbase =
        (const float4*)(item_emb + ((size_t)iid * M_TOT + 1) * CDIM);

    float* X = xpose + w * 780;

    // rows in batches of 4: issue all 8 loads, then consume (MLP = 8)
#pragma unroll
    for (int mb = 0; mb < 12; mb += 4) {
        float4 a[4], b[4];
#pragma unroll
        for (int j = 0; j < 4; ++j) {
            int m = mb + j;
            if (m < nb) {
                const float4* vr = vbase + (size_t)m * (CDIM / 4);
                a[j] = vr[l];
                b[j] = vr[l + 16];
            }
        }
#pragma unroll
        for (int j = 0; j < 4; ++j) {
            int m = mb + j;
            if (m < nb) {
                float d0 = u0.x - a[j].x, d1 = u0.y - a[j].y;
                float d2 = u0.z - a[j].z, d3 = u0.w - a[j].w;
                float d4 = u1.x - b[j].x, d5 = u1.y - b[j].y;
                float d6 = u1.z - b[j].z, d7 = u1.w - b[j].w;
                X[m * 65 + g * 16 + l] =
                    ((d0 * d0 + d1 * d1) + (d2 * d2 + d3 * d3))
                  + ((d4 * d4 + d5 * d5) + (d6 * d6 + d7 * d7));
            }
        }
    }

    __syncthreads();

    // lane m sums row m's 16 partials (serial, f32)
    int lm = (l < 12) ? l : 0;
    const float* R = X + lm * 65 + g * 16;
    float t0 = 0.f, t1 = 0.f, t2 = 0.f, t3 = 0.f;
#pragma unroll
    for (int r = 0; r < 4; ++r) {
        t0 += R[r];
        t1 += R[4 + r];
        t2 += R[8 + r];
        t3 += R[12 + r];
    }
    float s = (t0 + t1) + (t2 + t3);
    if (l >= nb) s = INFINITY;

    // single 16-lane argmin butterfly tracking (best, idx, second-best)
    float b1 = s, b2 = INFINITY;
    int i1 = l + 1;
#pragma unroll
    for (int off = 1; off < 16; off <<= 1) {
        float ob1 = __shfl_xor(b1, off);
        float ob2 = __shfl_xor(b2, off);
        int   oi1 = __shfl_xor(i1, off);
        float lo = fminf(b1, ob1);
        float hi = fmaxf(b1, ob1);
        if (ob1 < b1 || (ob1 == b1 && oi1 < i1)) i1 = oi1;
        b1 = lo;
        b2 = fminf(fminf(b2, ob2), hi);
    }

    if (l == 0 && vq) {
        out[q] = (float)(i1 - 1) / (float)(nb - 1) + 1.0f;
        if (b2 - b1 < TAU && flag_cnt) {
            int pos = atomicAdd(flag_cnt, 1);
            flag_list[pos] = q;
        }
    }
}

// ---------------- exact f64 refinement (rare) ----------------
__global__ __launch_bounds__(256) void impact_refine(
    const int* __restrict__ user_ids,
    const int* __restrict__ item_ids,
    const float* __restrict__ users_emb,
    const float* __restrict__ item_emb,
    const int* __restrict__ nb_mod,
    const int* __restrict__ flag_cnt,
    const int* __restrict__ flag_list,
    float* __restrict__ out)
{
    int cnt = *flag_cnt;
    int ngrp = (gridDim.x * blockDim.x) >> 4;
    int gid = (blockIdx.x * blockDim.x + threadIdx.x) >> 4;
    int l = threadIdx.x & 15;

    for (int i = gid; i < cnt; i += ngrp) {
        int q = flag_list[i];
        int uid = user_ids[q];
        int iid = item_ids[q];
        int nb  = nb_mod[iid];

        const float4* urow = (const float4*)(users_emb + (size_t)uid * CDIM);
        float4 u0 = urow[l];
        float4 u1 = urow[l + 16];

        double best = 1e300;
        int bidx = 1;
        const float4* ibase =
            (const float4*)(item_emb + ((size_t)iid * M_TOT + 1) * CDIM);

        for (int m = 1; m <= nb; ++m) {
            const float4* vr = ibase + (size_t)(m - 1) * (CDIM / 4);
            float4 v0 = vr[l];
            float4 v1 = vr[l + 16];
            float d;
            double sd = 0.0;
            d = u0.x - v0.x; sd += (double)d * d;
            d = u0.y - v0.y; sd += (double)d * d;
            d = u0.z - v0.z; sd += (double)d * d;
            d = u0.w - v0.w; sd += (double)d * d;
            d = u1.x - v1.x; sd += (double)d * d;
            d = u1.y - v1.y; sd += (double)d * d;
            d = u1.z - v1.z; sd += (double)d * d;
            d = u1.w - v1.w; sd += (double)d * d;
            sd += __shfl_xor(sd, 1);
            sd += __shfl_xor(sd, 2);
            sd += __shfl_xor(sd, 4);
            sd += __shfl_xor(sd, 8);
            if (sd < best) { best = sd; bidx = m; }
        }
        if (l == 0)
            out[q] = (float)(bidx - 1) / (float)(nb - 1) + 1.0f;
    }
}

extern "C" void kernel_launch(void* const* d_in, const int* in_sizes, int n_in,
                              void* d_out, int out_size, void* d_ws, size_t ws_size,
                              hipStream_t stream) {
    // inputs: 0 user_ids, 1 item_ids, 2 concept_ids (unused),
    //         3 users_emb_weight, 4 item_resp_emb_weight,
    //         5 mask (unused; nb_modalities carries the same info), 6 nb_modalities
    const int*   user_ids  = (const int*)d_in[0];
    const int*   item_ids  = (const int*)d_in[1];
    const float* users_emb = (const float*)d_in[3];
    const float* item_emb  = (const float*)d_in[4];
    const int*   nb_mod    = (const int*)d_in[6];
    float* out = (float*)d_out;

    int B = in_sizes[0];
    int n_items = in_sizes[6];
    int nblk = (n_items + 255) >> 8;   // scan chunks of 256

    // ws layout (ints): hist[n] | flag_cnt[1] pad[3] | cursor[n]
    //                   | bsum[128] | boffs[128] | perm[B] | flag_list[B]
    size_t need = ((size_t)n_items * 2 + 4 + 256 + 2 * (size_t)B) * sizeof(int);
    int* hist      = (int*)d_ws;
    int* flag_cnt  = hist + n_items;
    int* cursor    = flag_cnt + 4;
    int* bsum      = cursor + n_items;
    int* boffs     = bsum + 128;
    int* perm      = boffs + 128;
    int* flag_list = perm + B;

    bool sorted = (ws_size >= need) && (nblk <= 128);
    if (sorted) {
        hipMemsetAsync(hist, 0, ((size_t)n_items + 4) * sizeof(int), stream);
        impact_hist<<<(B / 4 + 255) / 256, 256, 0, stream>>>(item_ids, hist, B);
        impact_scan_part<<<nblk, 256, 0, stream>>>(hist, cursor, bsum, n_items);
        impact_scan_top<<<1, 128, 0, stream>>>(bsum, boffs, nblk);
        impact_scatter<<<(B / 4 + 255) / 256, 256, 0, stream>>>(
            item_ids, cursor, boffs, perm, B);
    }

    int grid = (B + 15) / 16;          // 16 queries per 256-thread block
    impact_main<<<grid, 256, 0, stream>>>(
        user_ids, item_ids, users_emb, item_emb, nb_mod,
        sorted ? perm : nullptr, out,
        sorted ? flag_cnt : nullptr, sorted ? flag_list : nullptr, B);

    if (sorted)
        impact_refine<<<64, 256, 0, stream>>>(
            user_ids, item_ids, users_emb, item_emb, nb_mod,
            flag_cnt, flag_list, out);
}